// Round 4
// baseline (545.922 us; speedup 1.0000x reference)
//
#include <hip/hip_runtime.h>

typedef __attribute__((ext_vector_type(4))) float float4v;

#define TY    8            // output rows per strip (block)
#define CXW   1024         // cols per block chunk
#define WXW   256          // cols per wave (64 lanes * 4)
#define WXP   (WXW + 8)    // LDS row width per wave (x-halo 4 each side)
#define NTHR  256
#define NWAVE (NTHR / 64)

__device__ __forceinline__ float4v ld4(const float* __restrict__ p) {
    return *(const float4v*)p;
}
__device__ __forceinline__ void st4(float* __restrict__ p, float4v v) {
    *(float4v*)p = v;
}
__device__ __forceinline__ float frcp(float x) {
    return __builtin_amdgcn_rcpf(x);
}

__device__ __forceinline__ void getC(int st, float C[4]) {
    C[0] = 1.f; C[1] = 0.f; C[2] = 0.f; C[3] = 0.f;
    if (st == 4)      { C[0] = 1.125f;          C[1] = -1.f / 24.f; }
    else if (st == 6) { C[0] = 75.f / 64.f;     C[1] = -25.f / 384.f;
                        C[2] = 3.f / 640.f; }
    else if (st == 8) { C[0] = 1225.f / 1024.f; C[1] = -245.f / 3072.f;
                        C[2] = 49.f / 5120.f;   C[3] = -5.f / 7168.f; }
}

// Wave-autonomous fused E+H update: each wave owns a 256-col sub-strip and a
// private Ey' LDS ring (incl. x-halo it computes itself). No cross-wave data
// flow -> ZERO __syncthreads; same-wave ds_write->ds_read ordering comes from
// compiler lgkmcnt. Waves free-run, keeping loads in flight continuously.
// Ring: H row h=r-ns taps Ey' rows r-2ns+1..r -> span 2ns. NSLOT=4 covers
// ns<=2, NSLOT=8 covers ns in {3,4}.
template<int NSLOT, int NSMIN, int NSMAX>
__global__ __launch_bounds__(NTHR, 4) void fdtd_fused(
    const float* __restrict__ ca,   const float* __restrict__ cb,
    const float* __restrict__ cq,
    const float* __restrict__ Ey,   const float* __restrict__ Hx,
    const float* __restrict__ Hz,
    const float* __restrict__ mHxz, const float* __restrict__ mHzx,
    const float* __restrict__ mEyx, const float* __restrict__ mEyz,
    const float* __restrict__ ky,   const float* __restrict__ kyh,
    const float* __restrict__ ay,   const float* __restrict__ ayh,
    const float* __restrict__ by,   const float* __restrict__ byh,
    const float* __restrict__ kx,   const float* __restrict__ kxh,
    const float* __restrict__ ax,   const float* __restrict__ axh,
    const float* __restrict__ bx,   const float* __restrict__ bxh,
    const float* __restrict__ rdyp, const float* __restrict__ rdxp,
    const int* __restrict__ stp,
    float* __restrict__ outEy,   float* __restrict__ outHx,
    float* __restrict__ outHz,   float* __restrict__ outMHxz,
    float* __restrict__ outMHzx, float* __restrict__ outMEyx,
    float* __restrict__ outMEyz,
    int B, int NY, int NX, int NSTRIP, int NCHUNK)
{
    int ns = stp[0] >> 1;
    if (ns < 1) ns = 1; if (ns > 4) ns = 4;
    if (ns < NSMIN || ns > NSMAX) return;

    __shared__ float eyl[NWAVE][NSLOT][WXP];

    // XCD-chunked swizzle: y-adjacent strips land on the same XCD L2.
    const int nwg = NSTRIP * NCHUNK;
    int idx = blockIdx.x;
    if ((nwg & 7) == 0) {
        const int q = nwg >> 3;
        idx = (idx & 7) * q + (idx >> 3);
    }
    const int strip = idx % NSTRIP;
    const int chunk = idx / NSTRIP;
    const int b   = blockIdx.y;
    const int y0  = strip * TY;
    const int X0  = chunk * CXW;

    const int tid  = (int)threadIdx.x;
    const int wid  = tid >> 6;
    const int lane = tid & 63;
    const int W0   = X0 + wid * WXW;   // wave's col origin
    const int x0   = W0 + lane * 4;    // owned cols x0..x0+3
    const int lc0  = lane * 4;         // LDS col of (x0 - 4)

    const float rdx = rdxp[0];
    const float rdy = rdyp[0];
    float C[4]; getC(ns * 2, C);

    const size_t NXs = (size_t)NX;
    const size_t planeOff = (size_t)b * (size_t)NY * NXs;
    const float4v z4 = {0.f, 0.f, 0.f, 0.f};
    const bool inX = (x0 + 4 <= NX);

    // per-thread x coefficients for the H update (row-invariant)
    float4v axhv = z4, bxhv = z4, rkxh = z4;
    if (inX) {
        float4v kxhv = ld4(kxh + x0);
        axhv = ld4(axh + x0); bxhv = ld4(bxh + x0);
        #pragma unroll
        for (int i = 0; i < 4; ++i) rkxh[i] = frcp(kxhv[i]);
    }

    // ---- Ey' for 4 cols starting at xb (4-aligned) of row r ----
    auto computeE = [&](int r, int xb, bool wr,
                        float ayv, float byv, float rky) -> float4v {
        if (r < 0 || r >= NY || xb < 0 || xb >= NX) return z4;
        const size_t rb = planeOff + (size_t)r * NXs;
        // Hz x-window: w[j] = Hz[r][xb-4+j], j = 0..11 (zero-padded)
        float w[12];
        {
            float4v l0 = (xb >= 4)       ? ld4(Hz + rb + (xb - 4)) : z4;
            float4v l1 =                   ld4(Hz + rb + xb);
            float4v l2 = (xb + 8 <= NX)  ? ld4(Hz + rb + xb + 4)   : z4;
            w[0]=l0.x; w[1]=l0.y; w[2] =l0.z; w[3] =l0.w;
            w[4]=l1.x; w[5]=l1.y; w[6] =l1.z; w[7] =l1.w;
            w[8]=l2.x; w[9]=l2.y; w[10]=l2.z; w[11]=l2.w;
        }
        float dzx[4] = {0.f,0.f,0.f,0.f}, dxz[4] = {0.f,0.f,0.f,0.f};
        #pragma unroll
        for (int k = 1; k <= 4; ++k) {
            if (k <= ns) {
                const float ck = C[k - 1];
                #pragma unroll
                for (int i = 0; i < 4; ++i)        // taps x+k-1, x-k
                    dzx[i] += ck * (w[i + 3 + k] - w[i + 4 - k]);
                const int yp = r + k - 1, ym = r - k;
                float4v up = (yp < NY) ? ld4(Hx + rb + (size_t)(k - 1) * NXs + xb) : z4;
                float4v dn = (ym >= 0) ? ld4(Hx + rb - (size_t)k * NXs + xb)       : z4;
                #pragma unroll
                for (int i = 0; i < 4; ++i)
                    dxz[i] += ck * (up[i] - dn[i]);
            }
        }
        const size_t cr = (size_t)r * NXs + (size_t)xb;
        float4v eyv = ld4(Ey   + rb + xb);
        float4v mzx = ld4(mHzx + rb + xb);
        float4v mxz = ld4(mHxz + rb + xb);
        float4v cav = ld4(ca + cr);
        float4v cbv = ld4(cb + cr);
        float4v kxv = ld4(kx + xb);
        float4v axv = ld4(ax + xb);
        float4v bxv = ld4(bx + xb);
        float4v oE, oMxz, oMzx;
        #pragma unroll
        for (int i = 0; i < 4; ++i) {
            const float dHzdx = dzx[i] * rdx;
            const float dHxdz = dxz[i] * rdy;
            const float mzx_n = bxv[i] * mzx[i] + axv[i] * dHzdx;
            const float mxz_n = byv    * mxz[i] + ayv    * dHxdz;
            oE[i] = cav[i] * eyv[i]
                  + cbv[i] * ((dHzdx * frcp(kxv[i]) + mzx_n)
                            - (dHxdz * rky          + mxz_n));
            oMxz[i] = mxz_n;
            oMzx[i] = mzx_n;
        }
        if (wr) {
            st4(outEy   + rb + xb, oE);
            st4(outMHxz + rb + xb, oMxz);
            st4(outMHzx + rb + xb, oMzx);
        }
        return oE;
    };

    // e = r - y0. E rows span [y0+1-ns, y0+TY+ns-1]; H row h = r - ns.
    for (int e = 1 - ns; e <= TY + ns - 1; ++e) {
        const int r = y0 + e;
        const int h = r - ns;
        const bool doH = (e >= ns) && (h < NY) && inX;

        // ---- prefetch H-row globals (independent of LDS/E) ----
        float4v hxv = z4, hzv = z4, mxv = z4, mzv = z4, cqv = z4;
        float ayhv = 0.f, byhv = 0.f, rkyh = 0.f;
        size_t hb = 0;
        if (doH) {
            hb  = planeOff + (size_t)h * NXs;
            hxv = ld4(Hx   + hb + x0);
            hzv = ld4(Hz   + hb + x0);
            mxv = ld4(mEyx + hb + x0);
            mzv = ld4(mEyz + hb + x0);
            cqv = ld4(cq + (size_t)h * NXs + x0);
            ayhv = ayh[h];
            byhv = byh[h];
            rkyh = frcp(kyh[h]);
        }

        // ---- E row r (zeros written to ring when r out of range) ----
        float ayv = 0.f, byv = 0.f, rky = 0.f;
        if (r >= 0 && r < NY) {
            ayv = ay[r]; byv = by[r]; rky = frcp(ky[r]);
        }
        const bool wr = (e >= 0) && (e < TY);
        float4v eM = computeE(r, x0, wr, ayv, byv, rky);
        float4v eHl = z4;
        if (lane == 0 || lane == 63) {       // wave's own x-halo cols
            const int xh = (lane == 0) ? W0 - 4 : W0 + WXW;
            eHl = computeE(r, xh, false, ayv, byv, rky);
        }

        const int slot = r & (NSLOT - 1);
        st4(&eyl[wid][slot][lc0 + 4], eM);
        if (lane == 0)  st4(&eyl[wid][slot][0],       eHl);
        if (lane == 63) st4(&eyl[wid][slot][WXW + 4], eHl);
        // Same-wave ds_write -> ds_read: ordered by compiler lgkmcnt waits.

        // ---- H row h (taps Ey' rows r-2ns+1 .. r, all in this wave's ring) --
        if (doH) {
            const int hs = h & (NSLOT - 1);
            // Ey' x-window: lw[j] = Ey'[h][x0-4+j], j = 0..11
            float lw[12];
            {
                float4v a0 = ld4(&eyl[wid][hs][lc0]);
                float4v a1 = ld4(&eyl[wid][hs][lc0 + 4]);
                float4v a2 = ld4(&eyl[wid][hs][lc0 + 8]);
                lw[0]=a0.x; lw[1]=a0.y; lw[2] =a0.z; lw[3] =a0.w;
                lw[4]=a1.x; lw[5]=a1.y; lw[6] =a1.z; lw[7] =a1.w;
                lw[8]=a2.x; lw[9]=a2.y; lw[10]=a2.z; lw[11]=a2.w;
            }
            float dEdx[4] = {0.f,0.f,0.f,0.f}, dEdz[4] = {0.f,0.f,0.f,0.f};
            #pragma unroll
            for (int k = 1; k <= 4; ++k) {
                if (k <= ns) {
                    const float ck = C[k - 1];
                    #pragma unroll
                    for (int i = 0; i < 4; ++i)      // taps x+k, x-k+1
                        dEdx[i] += ck * (lw[i + 4 + k] - lw[i + 5 - k]);
                    float4v up = ld4(&eyl[wid][(h + k)     & (NSLOT - 1)][lc0 + 4]);
                    float4v dn = ld4(&eyl[wid][(h - k + 1) & (NSLOT - 1)][lc0 + 4]);
                    #pragma unroll
                    for (int i = 0; i < 4; ++i)
                        dEdz[i] += ck * (up[i] - dn[i]);
                }
            }
            float4v oHx, oHz, oMx, oMz;
            #pragma unroll
            for (int i = 0; i < 4; ++i) {
                const float dz = dEdz[i] * rdy;      // dEy_dz
                const float dx = dEdx[i] * rdx;      // dEy_dx
                const float mz_n = byhv    * mzv[i] + ayhv    * dz;
                const float mx_n = bxhv[i] * mxv[i] + axhv[i] * dx;
                oHx[i] = hxv[i] - cqv[i] * (dz * rkyh    + mz_n);
                oHz[i] = hzv[i] + cqv[i] * (dx * rkxh[i] + mx_n);
                oMx[i] = mx_n;
                oMz[i] = mz_n;
            }
            st4(outHx   + hb + x0, oHx);
            st4(outHz   + hb + x0, oHz);
            st4(outMEyx + hb + x0, oMx);
            st4(outMEyz + hb + x0, oMz);
        }
    }
}

extern "C" void kernel_launch(void* const* d_in, const int* in_sizes, int n_in,
                              void* d_out, int out_size, void* d_ws, size_t ws_size,
                              hipStream_t stream)
{
    const float* ca   = (const float*)d_in[0];
    const float* cb   = (const float*)d_in[1];
    const float* cq   = (const float*)d_in[2];
    const float* Ey   = (const float*)d_in[3];
    const float* Hx   = (const float*)d_in[4];
    const float* Hz   = (const float*)d_in[5];
    const float* mHxz = (const float*)d_in[6];
    const float* mHzx = (const float*)d_in[7];
    const float* mEyx = (const float*)d_in[8];
    const float* mEyz = (const float*)d_in[9];
    const float* ky   = (const float*)d_in[10];
    const float* kyh  = (const float*)d_in[11];
    const float* ay   = (const float*)d_in[12];
    const float* ayh  = (const float*)d_in[13];
    const float* by   = (const float*)d_in[14];
    const float* byh  = (const float*)d_in[15];
    const float* kx   = (const float*)d_in[16];
    const float* kxh  = (const float*)d_in[17];
    const float* ax   = (const float*)d_in[18];
    const float* axh  = (const float*)d_in[19];
    const float* bx   = (const float*)d_in[20];
    const float* bxh  = (const float*)d_in[21];
    const float* rdy  = (const float*)d_in[22];
    const float* rdx  = (const float*)d_in[23];
    const int*   stp  = (const int*)d_in[24];

    const int NX   = in_sizes[16];
    const int NYNX = in_sizes[0];
    const int NY   = NYNX / NX;
    const int B    = in_sizes[3] / NYNX;
    const size_t plane = (size_t)B * (size_t)NYNX;

    float* out     = (float*)d_out;
    float* outEy   = out;
    float* outHx   = out + 1 * plane;
    float* outHz   = out + 2 * plane;
    float* outMHxz = out + 3 * plane;
    float* outMHzx = out + 4 * plane;
    float* outMEyx = out + 5 * plane;
    float* outMEyz = out + 6 * plane;

    const int NSTRIP = (NY + TY - 1) / TY;
    const int NCHUNK = (NX + CXW - 1) / CXW;

    dim3 grid(NSTRIP * NCHUNK, B);
    dim3 block(NTHR);

    // ns <= 2 path (bench: stencil=4 -> ns=2), 4-slot ring
    fdtd_fused<4, 1, 2><<<grid, block, 0, stream>>>(
        ca, cb, cq, Ey, Hx, Hz, mHxz, mHzx, mEyx, mEyz,
        ky, kyh, ay, ayh, by, byh, kx, kxh, ax, axh, bx, bxh,
        rdy, rdx, stp,
        outEy, outHx, outHz, outMHxz, outMHzx, outMEyx, outMEyz,
        B, NY, NX, NSTRIP, NCHUNK);

    // ns in {3,4} fallback, 8-slot ring (early-exits when unused)
    fdtd_fused<8, 3, 4><<<grid, block, 0, stream>>>(
        ca, cb, cq, Ey, Hx, Hz, mHxz, mHzx, mEyx, mEyz,
        ky, kyh, ay, ayh, by, byh, kx, kxh, ax, axh, bx, bxh,
        rdy, rdx, stp,
        outEy, outHx, outHz, outMHxz, outMHzx, outMEyx, outMEyz,
        B, NY, NX, NSTRIP, NCHUNK);
}

// Round 5
// 499.190 us; speedup vs baseline: 1.0936x; 1.0936x over previous
//
#include <hip/hip_runtime.h>

typedef __attribute__((ext_vector_type(4))) float float4v;

#define TY    8            // output rows per strip
#define WXW   256          // cols per wave (64 lanes * 4)
#define WXP   (WXW + 8)    // LDS row width (x-halo 4 each side)

__device__ __forceinline__ float4v ld4(const float* __restrict__ p) {
    return *(const float4v*)p;
}
__device__ __forceinline__ void st4(float* __restrict__ p, float4v v) {
    *(float4v*)p = v;
}
__device__ __forceinline__ float frcp(float x) {
    return __builtin_amdgcn_rcpf(x);
}

// Wave-autonomous fused E+H update, compile-time stencil radius NS.
// One 64-thread wave per block owns a 256-col x TY-row tile.
// Register rings: Hx (depth NSLOT, rows r-NS..r+NS-1), Hz center (reused as
// H-phase Hz load). LDS ring only for Ey' (x-neighbor exchange), no barriers
// (same-wave DS ordering). All ring slots compile-time after unroll.
template<int NS>
__global__ __launch_bounds__(64) void fdtd_ns(
    const float* __restrict__ ca,   const float* __restrict__ cb,
    const float* __restrict__ cq,
    const float* __restrict__ Ey,   const float* __restrict__ Hx,
    const float* __restrict__ Hz,
    const float* __restrict__ mHxz, const float* __restrict__ mHzx,
    const float* __restrict__ mEyx, const float* __restrict__ mEyz,
    const float* __restrict__ ky,   const float* __restrict__ kyh,
    const float* __restrict__ ay,   const float* __restrict__ ayh,
    const float* __restrict__ by,   const float* __restrict__ byh,
    const float* __restrict__ kx,   const float* __restrict__ kxh,
    const float* __restrict__ ax,   const float* __restrict__ axh,
    const float* __restrict__ bx,   const float* __restrict__ bxh,
    const float* __restrict__ rdyp, const float* __restrict__ rdxp,
    const int* __restrict__ stp,
    float* __restrict__ outEy,   float* __restrict__ outHx,
    float* __restrict__ outHz,   float* __restrict__ outMHxz,
    float* __restrict__ outMHzx, float* __restrict__ outMEyx,
    float* __restrict__ outMEyz,
    int B, int NY, int NX, int NSTRIP, int NWX)
{
    int nsr = stp[0] >> 1;
    if (nsr < 1) nsr = 1; if (nsr > 4) nsr = 4;
    if (nsr != NS) return;                 // wrong instantiation: early-exit

    constexpr int NSLOT = (NS <= 2) ? 4 : 8;   // >= 2*NS
    __shared__ float eyl[NSLOT][WXP];

    float C[4] = {0.f, 0.f, 0.f, 0.f};
    if constexpr (NS == 1)      { C[0] = 1.f; }
    else if constexpr (NS == 2) { C[0] = 1.125f;          C[1] = -1.f/24.f; }
    else if constexpr (NS == 3) { C[0] = 75.f/64.f;       C[1] = -25.f/384.f;
                                  C[2] = 3.f/640.f; }
    else                        { C[0] = 1225.f/1024.f;   C[1] = -245.f/3072.f;
                                  C[2] = 49.f/5120.f;     C[3] = -5.f/7168.f; }

    // XCD swizzle: XCD c owns the full-height panel wx==c (strip varies fastest)
    const int nwg = NSTRIP * NWX;
    int idx = blockIdx.x;
    if ((nwg & 7) == 0) {
        const int q = nwg >> 3;
        idx = (idx & 7) * q + (idx >> 3);
    }
    const int strip = idx % NSTRIP;
    const int wx    = idx / NSTRIP;
    const int b  = blockIdx.y;
    const int y0 = strip * TY;             // multiple of 8 -> y0 & (NSLOT-1) == 0
    const int W0 = wx * WXW;
    const int lane = (int)threadIdx.x & 63;
    const int x0  = W0 + lane * 4;
    const int lc0 = lane * 4;

    const float rdx = rdxp[0];
    const float rdy = rdyp[0];
    const size_t NXs = (size_t)NX;
    const size_t planeOff = (size_t)b * (size_t)NY * NXs;
    const float4v z4 = {0.f, 0.f, 0.f, 0.f};
    const bool inX    = (x0 + 4 <= NX);
    const bool isHalo = (lane == 0) || (lane == 63);
    const int  xh     = (lane == 0) ? (W0 - 4) : (W0 + WXW);
    const bool haloIn = isHalo && (xh >= 0) && (xh + 4 <= NX);

    // hoisted row-invariant x coefficients
    float4v rkx = z4, axv = z4, bxv = z4, rkxh = z4, axhv = z4, bxhv = z4;
    if (inX) {
        float4v t = ld4(kx + x0);
        #pragma unroll
        for (int i = 0; i < 4; ++i) rkx[i] = frcp(t[i]);
        axv = ld4(ax + x0); bxv = ld4(bx + x0);
        t = ld4(kxh + x0);
        #pragma unroll
        for (int i = 0; i < 4; ++i) rkxh[i] = frcp(t[i]);
        axhv = ld4(axh + x0); bxhv = ld4(bxh + x0);
    }
    float4v rkxH = z4, axvH = z4, bxvH = z4;
    if (haloIn) {
        float4v t = ld4(kx + xh);
        #pragma unroll
        for (int i = 0; i < 4; ++i) rkxH[i] = frcp(t[i]);
        axvH = ld4(ax + xh); bxvH = ld4(bx + xh);
    }

    // register rings; slot = row & (NSLOT-1); OOB rows hold zeros
    float4v hxr[NSLOT], hzc[NSLOT];
    #pragma unroll
    for (int j = 0; j < NSLOT; ++j) { hxr[j] = z4; hzc[j] = z4; }
    #pragma unroll
    for (int j = 0; j < 2*NS - 1; ++j) {       // prologue rows y0+1-2NS..y0-1
        const int rr = y0 + 1 - 2*NS + j;
        if (rr >= 0 && inX)
            hxr[rr & (NSLOT-1)] = ld4(Hx + planeOff + (size_t)rr * NXs + x0);
    }

    constexpr int NITER = TY + 2*NS - 1;
    constexpr int NCH   = (NITER + NSLOT - 1) / NSLOT;
    for (int mch = 0; mch < NCH; ++mch) {
        #pragma unroll
        for (int j = 0; j < NSLOT; ++j) {
            const int e = 1 - NS + mch * NSLOT + j;   // slot masks fold to j-consts
            if (e > TY + NS - 1) break;               // uniform tail guard
            const int r = y0 + e;
            const int h = r - NS;
            const bool rin = (r >= 0) && (r < NY);
            const bool doH = (e >= NS) && (h < NY) && inX;
            const size_t rb = planeOff + (size_t)r * NXs;

            // ---- H prefetch: rings + 3 loads (hide under E compute) ----
            float4v hxv = z4, hzv = z4, mxv = z4, mzv = z4, cqv = z4;
            float ayhv = 0.f, byhv = 0.f, rkyh = 0.f;
            size_t hb = 0;
            if (doH) {
                hb  = planeOff + (size_t)h * NXs;
                hxv = hxr[h & (NSLOT-1)];
                hzv = hzc[h & (NSLOT-1)];
                mxv = ld4(mEyx + hb + x0);
                mzv = ld4(mEyz + hb + x0);
                cqv = ld4(cq + (size_t)h * NXs + x0);
                ayhv = ayh[h]; byhv = byh[h]; rkyh = frcp(kyh[h]);
            }

            // ---- Hx ring advance: row r+NS-1 loaded exactly once ----
            {
                const int rr = r + NS - 1;            // >= 0 always
                hxr[rr & (NSLOT-1)] =
                    (rr < NY && inX) ? ld4(Hx + planeOff + (size_t)rr * NXs + x0)
                                     : z4;
            }

            // ---- E row r, own 4 cols ----
            float ayv = 0.f, byv = 0.f, rky = 0.f;
            if (rin) { ayv = ay[r]; byv = by[r]; rky = frcp(ky[r]); }
            float4v eM = z4;
            if (rin && inX) {
                float4v l0 = (x0 >= 4)      ? ld4(Hz + rb + x0 - 4) : z4;
                float4v l1 =                  ld4(Hz + rb + x0);
                float4v l2 = (x0 + 8 <= NX) ? ld4(Hz + rb + x0 + 4) : z4;
                hzc[r & (NSLOT-1)] = l1;              // reused as H's Hz load
                float w[12] = {l0.x,l0.y,l0.z,l0.w, l1.x,l1.y,l1.z,l1.w,
                               l2.x,l2.y,l2.z,l2.w};
                float dzx[4] = {0,0,0,0}, dxz[4] = {0,0,0,0};
                #pragma unroll
                for (int k = 1; k <= NS; ++k) {
                    const float ck = C[k-1];
                    #pragma unroll
                    for (int i = 0; i < 4; ++i)       // taps x+k-1, x-k
                        dzx[i] += ck * (w[i+3+k] - w[i+4-k]);
                    float4v up = hxr[(r+k-1) & (NSLOT-1)];
                    float4v dn = hxr[(r-k)   & (NSLOT-1)];
                    #pragma unroll
                    for (int i = 0; i < 4; ++i)
                        dxz[i] += ck * (up[i] - dn[i]);
                }
                float4v eyv = ld4(Ey   + rb + x0);
                float4v mzx = ld4(mHzx + rb + x0);
                float4v mxz = ld4(mHxz + rb + x0);
                const size_t crr = (size_t)r * NXs + x0;
                float4v cav = ld4(ca + crr);
                float4v cbv = ld4(cb + crr);
                float4v oMxz, oMzx;
                #pragma unroll
                for (int i = 0; i < 4; ++i) {
                    const float dHzdx = dzx[i] * rdx;
                    const float dHxdz = dxz[i] * rdy;
                    const float mzx_n = bxv[i] * mzx[i] + axv[i] * dHzdx;
                    const float mxz_n = byv    * mxz[i] + ayv    * dHxdz;
                    eM[i] = cav[i] * eyv[i]
                          + cbv[i] * ((dHzdx * rkx[i] + mzx_n)
                                    - (dHxdz * rky    + mxz_n));
                    oMxz[i] = mxz_n; oMzx[i] = mzx_n;
                }
                if (e >= 0 && e < TY) {
                    st4(outEy   + rb + x0, eM);
                    st4(outMHxz + rb + x0, oMxz);
                    st4(outMHzx + rb + x0, oMzx);
                }
            }

            // ---- E row r, wave's x-halo cols (lanes 0 / 63) ----
            float4v eH = z4;
            if (haloIn && rin) {
                float4v l0 = (xh >= 4)      ? ld4(Hz + rb + xh - 4) : z4;
                float4v l1 =                  ld4(Hz + rb + xh);
                float4v l2 = (xh + 8 <= NX) ? ld4(Hz + rb + xh + 4) : z4;
                float w[12] = {l0.x,l0.y,l0.z,l0.w, l1.x,l1.y,l1.z,l1.w,
                               l2.x,l2.y,l2.z,l2.w};
                float dzx[4] = {0,0,0,0}, dxz[4] = {0,0,0,0};
                #pragma unroll
                for (int k = 1; k <= NS; ++k) {
                    const float ck = C[k-1];
                    #pragma unroll
                    for (int i = 0; i < 4; ++i)
                        dzx[i] += ck * (w[i+3+k] - w[i+4-k]);
                    const int yp = r + k - 1, ym = r - k;
                    float4v up = (yp < NY) ? ld4(Hx + planeOff + (size_t)yp*NXs + xh) : z4;
                    float4v dn = (ym >= 0) ? ld4(Hx + planeOff + (size_t)ym*NXs + xh) : z4;
                    #pragma unroll
                    for (int i = 0; i < 4; ++i)
                        dxz[i] += ck * (up[i] - dn[i]);
                }
                float4v eyv = ld4(Ey   + rb + xh);
                float4v mzx = ld4(mHzx + rb + xh);
                float4v mxz = ld4(mHxz + rb + xh);
                const size_t crr = (size_t)r * NXs + xh;
                float4v cav = ld4(ca + crr);
                float4v cbv = ld4(cb + crr);
                #pragma unroll
                for (int i = 0; i < 4; ++i) {
                    const float dHzdx = dzx[i] * rdx;
                    const float dHxdz = dxz[i] * rdy;
                    const float mzx_n = bxvH[i] * mzx[i] + axvH[i] * dHzdx;
                    const float mxz_n = byv     * mxz[i] + ayv     * dHxdz;
                    eH[i] = cav[i] * eyv[i]
                          + cbv[i] * ((dHzdx * rkxH[i] + mzx_n)
                                    - (dHxdz * rky     + mxz_n));
                }
            }

            // ---- publish Ey' row r to wave-private LDS ring ----
            const int sl = r & (NSLOT-1);
            st4(&eyl[sl][lc0 + 4], eM);
            if (lane == 0)  st4(&eyl[sl][0],       eH);
            if (lane == 63) st4(&eyl[sl][WXW + 4], eH);
            // same-wave ds_write -> ds_read ordering; no barrier needed

            // ---- H row h (taps rows h-NS+1..h+NS = r-2NS+1..r, all live) ----
            if (doH) {
                const int hs = h & (NSLOT-1);
                float4v a0 = ld4(&eyl[hs][lc0]);
                float4v a1 = ld4(&eyl[hs][lc0 + 4]);
                float4v a2 = ld4(&eyl[hs][lc0 + 8]);
                float lw[12] = {a0.x,a0.y,a0.z,a0.w, a1.x,a1.y,a1.z,a1.w,
                                a2.x,a2.y,a2.z,a2.w};
                float dEdx[4] = {0,0,0,0}, dEdz[4] = {0,0,0,0};
                #pragma unroll
                for (int k = 1; k <= NS; ++k) {
                    const float ck = C[k-1];
                    #pragma unroll
                    for (int i = 0; i < 4; ++i)       // taps x+k, x-k+1
                        dEdx[i] += ck * (lw[i+4+k] - lw[i+5-k]);
                    float4v up = ld4(&eyl[(h+k)   & (NSLOT-1)][lc0 + 4]);
                    float4v dn = ld4(&eyl[(h-k+1) & (NSLOT-1)][lc0 + 4]);
                    #pragma unroll
                    for (int i = 0; i < 4; ++i)
                        dEdz[i] += ck * (up[i] - dn[i]);
                }
                float4v oHx, oHz, oMx, oMz;
                #pragma unroll
                for (int i = 0; i < 4; ++i) {
                    const float dz = dEdz[i] * rdy;   // dEy_dz
                    const float dx = dEdx[i] * rdx;   // dEy_dx
                    const float mz_n = byhv    * mzv[i] + ayhv    * dz;
                    const float mx_n = bxhv[i] * mxv[i] + axhv[i] * dx;
                    oHx[i] = hxv[i] - cqv[i] * (dz * rkyh    + mz_n);
                    oHz[i] = hzv[i] + cqv[i] * (dx * rkxh[i] + mx_n);
                    oMx[i] = mx_n; oMz[i] = mz_n;
                }
                st4(outHx   + hb + x0, oHx);
                st4(outHz   + hb + x0, oHz);
                st4(outMEyx + hb + x0, oMx);
                st4(outMEyz + hb + x0, oMz);
            }
        }
    }
}

extern "C" void kernel_launch(void* const* d_in, const int* in_sizes, int n_in,
                              void* d_out, int out_size, void* d_ws, size_t ws_size,
                              hipStream_t stream)
{
    const float* ca   = (const float*)d_in[0];
    const float* cb   = (const float*)d_in[1];
    const float* cq   = (const float*)d_in[2];
    const float* Ey   = (const float*)d_in[3];
    const float* Hx   = (const float*)d_in[4];
    const float* Hz   = (const float*)d_in[5];
    const float* mHxz = (const float*)d_in[6];
    const float* mHzx = (const float*)d_in[7];
    const float* mEyx = (const float*)d_in[8];
    const float* mEyz = (const float*)d_in[9];
    const float* ky   = (const float*)d_in[10];
    const float* kyh  = (const float*)d_in[11];
    const float* ay   = (const float*)d_in[12];
    const float* ayh  = (const float*)d_in[13];
    const float* by   = (const float*)d_in[14];
    const float* byh  = (const float*)d_in[15];
    const float* kx   = (const float*)d_in[16];
    const float* kxh  = (const float*)d_in[17];
    const float* ax   = (const float*)d_in[18];
    const float* axh  = (const float*)d_in[19];
    const float* bx   = (const float*)d_in[20];
    const float* bxh  = (const float*)d_in[21];
    const float* rdy  = (const float*)d_in[22];
    const float* rdx  = (const float*)d_in[23];
    const int*   stp  = (const int*)d_in[24];

    const int NX   = in_sizes[16];
    const int NYNX = in_sizes[0];
    const int NY   = NYNX / NX;
    const int B    = in_sizes[3] / NYNX;
    const size_t plane = (size_t)B * (size_t)NYNX;

    float* out     = (float*)d_out;
    float* outEy   = out;
    float* outHx   = out + 1 * plane;
    float* outHz   = out + 2 * plane;
    float* outMHxz = out + 3 * plane;
    float* outMHzx = out + 4 * plane;
    float* outMEyx = out + 5 * plane;
    float* outMEyz = out + 6 * plane;

    const int NSTRIP = (NY + TY - 1) / TY;
    const int NWX    = (NX + WXW - 1) / WXW;

    dim3 grid(NSTRIP * NWX, B);
    dim3 block(64);

    #define LAUNCH(NSV)                                                      \
        fdtd_ns<NSV><<<grid, block, 0, stream>>>(                            \
            ca, cb, cq, Ey, Hx, Hz, mHxz, mHzx, mEyx, mEyz,                  \
            ky, kyh, ay, ayh, by, byh, kx, kxh, ax, axh, bx, bxh,            \
            rdy, rdx, stp,                                                   \
            outEy, outHx, outHz, outMHxz, outMHzx, outMEyx, outMEyz,         \
            B, NY, NX, NSTRIP, NWX)

    LAUNCH(2);   // bench path first (stencil=4)
    LAUNCH(1);
    LAUNCH(3);
    LAUNCH(4);
    #undef LAUNCH
}